// Round 1
// baseline (124.626 us; speedup 1.0000x reference)
//
#include <hip/hip_runtime.h>
#include <hip/hip_bf16.h>

// Problem constants (fixed by reference).
#define BN 65536   // batch
#define FD 128     // feature dim (K of layer 1)
#define HD 256     // hidden dim (N of layer 1)
#define DN 8       // domains
#define NB 256     // histogram blocks (BN / 256)
#define TM 128     // rows (samples) per main-kernel tile
#define MAXT (BN / TM + DN)   // 520 upper bound on tiles

typedef float f32x4 __attribute__((ext_vector_type(4)));
using bf16x8 = __attribute__((ext_vector_type(8))) __bf16;

union BF8 { bf16x8 v; unsigned short u[8]; };

__device__ __forceinline__ unsigned short f2bf(float f) {
  unsigned int x = __float_as_uint(f);
  x += 0x7fffu + ((x >> 16) & 1u);   // round-to-nearest-even
  return (unsigned short)(x >> 16);
}

// ---- Kw: W1 (D,F,H) f32  ->  W1T (D,H,F) bf16 so B-fragments are 16B/lane contiguous.
__global__ void kw(const float* __restrict__ W1, unsigned short* __restrict__ W1T) {
  int o = blockIdx.x * 256 + threadIdx.x;     // 262144 elements
  int d = o >> 15;
  int rem = o & 32767;
  int h = rem >> 7;     // HD index
  int f = rem & 127;    // FD index
  W1T[o] = f2bf(W1[(d * FD + f) * HD + h]);
}

// ---- K1: per-block domain histogram + per-sample local position (LDS atomics only).
__global__ void k1(const int* __restrict__ ids, int* __restrict__ local_pos,
                   int* __restrict__ cnt_blk) {
  __shared__ int hist[DN];
  int t = threadIdx.x;
  if (t < DN) hist[t] = 0;
  __syncthreads();
  int i = blockIdx.x * 256 + t;
  int id = ids[i];
  local_pos[i] = atomicAdd(&hist[id], 1);
  __syncthreads();
  if (t < DN) cnt_blk[blockIdx.x * DN + t] = hist[t];
}

// ---- K2: per-domain prefix over blocks (one wave per domain), domain offsets, tile table.
__global__ void k2(const int* __restrict__ cnt_blk, int* __restrict__ blk_base,
                   int* __restrict__ dom_off, int* __restrict__ tile_d,
                   int* __restrict__ tile_start, int* __restrict__ tile_rows,
                   int* __restrict__ n_tiles) {
  __shared__ int s_cnt[DN], s_off[DN], s_T[DN + 1];
  int t = threadIdx.x;       // 512 threads = 8 waves, wave d handles domain d
  int d = t >> 6;
  int l = t & 63;
  int c[4];
  int sum = 0;
#pragma unroll
  for (int j = 0; j < 4; j++) { c[j] = cnt_blk[(l * 4 + j) * DN + d]; sum += c[j]; }
  int run = sum;                          // inclusive wave scan of per-lane sums
  for (int off = 1; off < 64; off <<= 1) {
    int v = __shfl_up(run, off);
    if (l >= off) run += v;
  }
  int excl = run - sum;
#pragma unroll
  for (int j = 0; j < 4; j++) { blk_base[(l * 4 + j) * DN + d] = excl; excl += c[j]; }
  if (l == 63) s_cnt[d] = run;            // domain total
  __syncthreads();
  if (t == 0) {
    int off = 0, T = 0;
    for (int dd = 0; dd < DN; dd++) {
      s_off[dd] = off; dom_off[dd] = off; off += s_cnt[dd];
      s_T[dd] = T; T += (s_cnt[dd] + TM - 1) / TM;
    }
    s_T[DN] = T;
    *n_tiles = T;
  }
  __syncthreads();
  int T = s_T[DN];
  for (int tt = t; tt < T; tt += 512) {
    int dd = 0;
    while (s_T[dd + 1] <= tt) dd++;
    int k = tt - s_T[dd];
    tile_d[tt] = dd;
    tile_start[tt] = s_off[dd] + k * TM;
    tile_rows[tt] = min(TM, s_cnt[dd] - k * TM);
  }
}

// ---- K3: scatter sample indices into per-domain contiguous lists.
__global__ void k3(const int* __restrict__ ids, const int* __restrict__ local_pos,
                   const int* __restrict__ blk_base, const int* __restrict__ dom_off,
                   int* __restrict__ perm) {
  __shared__ int base[DN];
  int t = threadIdx.x;
  if (t < DN) base[t] = dom_off[t] + blk_base[blockIdx.x * DN + t];
  __syncthreads();
  int i = blockIdx.x * 256 + t;
  perm[base[ids[i]] + local_pos[i]] = i;
}

// ---- Kmain: per (domain, 128-sample tile): h = relu(x W1 + b1); out = h.W2 + b2.
// 8 waves: wave = (nhalf<<2) | mgroup. Wave computes 32 rows x 128 cols via
// mfma_f32_16x16x32_bf16, fragments straight from global (weights are L2-resident).
// A layout: row = lane&15, k = 8*(lane>>4)+e.  B: col = lane&15, k = 8*(lane>>4)+e.
// C/D (measured m89): col = lane&15, row = (lane>>4)*4 + reg.
__global__ __launch_bounds__(512) void kmain(
    const float* __restrict__ x, const float* __restrict__ b1,
    const float* __restrict__ W2, const float* __restrict__ b2,
    const unsigned short* __restrict__ W1T, const int* __restrict__ perm,
    const int* __restrict__ tile_d, const int* __restrict__ tile_start,
    const int* __restrict__ tile_rows, const int* __restrict__ n_tiles,
    float* __restrict__ out) {
  int bid = blockIdx.x;
  if (bid >= *n_tiles) return;
  int d = tile_d[bid];
  int start = tile_start[bid];
  int rows = tile_rows[bid];

  __shared__ int s_perm[TM];
  __shared__ float s_red[TM][2];

  int t = threadIdx.x;
  if (t < TM) s_perm[t] = perm[start + min(t, rows - 1)];
  __syncthreads();

  int lane = t & 63;
  int wave = t >> 6;
  int nhalf = wave >> 2;          // 0: cols 0-127, 1: cols 128-255
  int mbase = (wave & 3) * 32;    // 32 rows per wave
  int lg = lane >> 4;             // k-group 0..3
  int lr = lane & 15;             // row/col within fragment

  const unsigned short* Wd = W1T + (size_t)d * HD * FD;   // [256][128] bf16
  const float* xr0 = x + (size_t)s_perm[mbase + lr] * FD;
  const float* xr1 = x + (size_t)s_perm[mbase + 16 + lr] * FD;

  f32x4 acc[2][8];
#pragma unroll
  for (int mt = 0; mt < 2; mt++)
#pragma unroll
    for (int nt = 0; nt < 8; nt++) acc[mt][nt] = (f32x4){0.f, 0.f, 0.f, 0.f};

#pragma unroll
  for (int ks = 0; ks < 4; ks++) {
    int k0 = ks * 32 + lg * 8;
    BF8 a0, a1;
    f32x4 u0 = *(const f32x4*)(xr0 + k0);
    f32x4 u1 = *(const f32x4*)(xr0 + k0 + 4);
    f32x4 v0 = *(const f32x4*)(xr1 + k0);
    f32x4 v1 = *(const f32x4*)(xr1 + k0 + 4);
#pragma unroll
    for (int j = 0; j < 4; j++) {
      a0.u[j] = f2bf(u0[j]); a0.u[4 + j] = f2bf(u1[j]);
      a1.u[j] = f2bf(v0[j]); a1.u[4 + j] = f2bf(v1[j]);
    }
#pragma unroll
    for (int nt = 0; nt < 8; nt++) {
      int n = nhalf * 128 + nt * 16 + lr;
      bf16x8 bf = *(const bf16x8*)(Wd + (size_t)n * FD + k0);
      acc[0][nt] = __builtin_amdgcn_mfma_f32_16x16x32_bf16(a0.v, bf, acc[0][nt], 0, 0, 0);
      acc[1][nt] = __builtin_amdgcn_mfma_f32_16x16x32_bf16(a1.v, bf, acc[1][nt], 0, 0, 0);
    }
  }

  // Fused layer 2 (fp32): relu(acc + b1) dot W2, reduced across the 16 lanes
  // that share a row group.
  float part[2][4] = {{0.f, 0.f, 0.f, 0.f}, {0.f, 0.f, 0.f, 0.f}};
#pragma unroll
  for (int nt = 0; nt < 8; nt++) {
    int c = nhalf * 128 + nt * 16 + lr;
    float b1v = b1[d * HD + c];
    float w2v = W2[d * HD + c];
#pragma unroll
    for (int mt = 0; mt < 2; mt++)
#pragma unroll
      for (int q = 0; q < 4; q++) {
        float h = acc[mt][nt][q] + b1v;
        h = h > 0.f ? h : 0.f;
        part[mt][q] = fmaf(h, w2v, part[mt][q]);
      }
  }
#pragma unroll
  for (int off = 1; off < 16; off <<= 1)
#pragma unroll
    for (int mt = 0; mt < 2; mt++)
#pragma unroll
      for (int q = 0; q < 4; q++)
        part[mt][q] += __shfl_xor(part[mt][q], off);

  if (lr == 0) {
#pragma unroll
    for (int mt = 0; mt < 2; mt++)
#pragma unroll
      for (int q = 0; q < 4; q++) {
        int r = mbase + mt * 16 + lg * 4 + q;
        s_red[r][nhalf] = part[mt][q];
      }
  }
  __syncthreads();
  if (t < rows) out[s_perm[t]] = s_red[t][0] + s_red[t][1] + b2[d];
}

extern "C" void kernel_launch(void* const* d_in, const int* in_sizes, int n_in,
                              void* d_out, int out_size, void* d_ws, size_t ws_size,
                              hipStream_t stream) {
  const float* x   = (const float*)d_in[0];
  const int*   ids = (const int*)d_in[1];
  const float* W1  = (const float*)d_in[2];
  const float* b1  = (const float*)d_in[3];
  const float* W2  = (const float*)d_in[4];
  const float* b2  = (const float*)d_in[5];
  float* out = (float*)d_out;

  // Workspace carving (ints), ~1.2 MB total.
  int* ws = (int*)d_ws;
  int* perm       = ws;                 // 65536
  int* local_pos  = ws + 65536;         // 65536
  int* cnt_blk    = ws + 131072;        // 2048
  int* blk_base   = ws + 133120;        // 2048
  int* dom_off    = ws + 135168;        // 8 (padded)
  int* tile_d     = ws + 135200;        // 520 (padded)
  int* tile_start = ws + 135760;        // 520 (padded)
  int* tile_rows  = ws + 136320;        // 520 (padded)
  int* n_tiles    = ws + 136880;        // 1
  unsigned short* W1T = (unsigned short*)((char*)d_ws + 640u * 1024u);  // 512 KB

  hipLaunchKernelGGL(kw, dim3(DN * FD * HD / 256), dim3(256), 0, stream, W1, W1T);
  hipLaunchKernelGGL(k1, dim3(NB), dim3(256), 0, stream, ids, local_pos, cnt_blk);
  hipLaunchKernelGGL(k2, dim3(1), dim3(512), 0, stream, cnt_blk, blk_base, dom_off,
                     tile_d, tile_start, tile_rows, n_tiles);
  hipLaunchKernelGGL(k3, dim3(NB), dim3(256), 0, stream, ids, local_pos, blk_base,
                     dom_off, perm);
  hipLaunchKernelGGL(kmain, dim3(MAXT), dim3(512), 0, stream, x, b1, W2, b2, W1T,
                     perm, tile_d, tile_start, tile_rows, n_tiles, out);
}

// Round 2
// 105.321 us; speedup vs baseline: 1.1833x; 1.1833x over previous
//
#include <hip/hip_runtime.h>
#include <hip/hip_bf16.h>

// Problem constants (fixed by reference).
#define BN 65536   // batch
#define FD 128     // feature dim (K of layer 1)
#define HD 256     // hidden dim (N of layer 1)
#define DN 8       // domains
#define TM 64      // rows (samples) per main-kernel tile
#define SLOTS 8192 // DN * (BN/TM) worst-case tile slots
#define GRID_MAIN 2048

typedef float f32x4 __attribute__((ext_vector_type(4)));
using bf16x8 = __attribute__((ext_vector_type(8))) __bf16;
typedef unsigned short us4 __attribute__((ext_vector_type(4)));

__device__ __forceinline__ unsigned short f2bf(float f) {
  unsigned int x = __float_as_uint(f);
  x += 0x7fffu + ((x >> 16) & 1u);   // round-to-nearest-even
  return (unsigned short)(x >> 16);
}

// ---- k_pre: fused (a) W1 [d][f][h] f32 -> W1T [d][h][f] bf16 via LDS-tile
// transpose (blocks 0..31), and (b) single-pass domain binning: per-block LDS
// histogram -> one global atomicAdd per (block,domain) -> scatter sample ids
// into fixed-capacity per-domain regions perm[d*65536 + ...].
__global__ __launch_bounds__(256) void k_pre(
    const float* __restrict__ W1, const int* __restrict__ ids,
    unsigned short* __restrict__ W1T, int* __restrict__ g_cnt,
    int* __restrict__ perm) {
  __shared__ int hist[DN], base[DN];
  __shared__ unsigned short tile[64][136];   // 64 h-rows x 128 f (+8 pad)
  int t = threadIdx.x, bid = blockIdx.x;

  if (t < DN) hist[t] = 0;
  __syncthreads();
  int i = bid * 256 + t;
  int id = ids[i];
  int lp = atomicAdd(&hist[id], 1);          // LDS atomic
  __syncthreads();
  if (t < DN) base[t] = atomicAdd(&g_cnt[t], hist[t]);   // 8 global atomics/block
  __syncthreads();
  perm[(id << 16) + base[id] + lp] = i;

  if (bid < 32) {                            // transpose W1 tile (d, h-quarter)
    int db = bid >> 2, hb = bid & 3;
    int fr = t >> 4, hq = t & 15;
    const float* src = W1 + (size_t)db * FD * HD + hb * 64 + hq * 4;
#pragma unroll
    for (int jj = 0; jj < 8; jj++) {
      int f = fr + 16 * jj;
      f32x4 v = *(const f32x4*)(src + (size_t)f * HD);
#pragma unroll
      for (int e = 0; e < 4; e++) tile[hq * 4 + e][f] = f2bf(v[e]);
    }
    __syncthreads();
    unsigned short* dst = W1T + (size_t)db * HD * FD + (size_t)hb * 64 * FD;
    int h = t >> 2, c = t & 3;
#pragma unroll
    for (int j = 0; j < 4; j++) {
      int f = c * 32 + j * 8;
      *(us4*)(dst + h * FD + f)     = *(const us4*)&tile[h][f];
      *(us4*)(dst + h * FD + f + 4) = *(const us4*)&tile[h][f + 4];
    }
  }
}

// ---- kmain: per (domain d, 64-sample tile k): h = relu(x W1 + b1); out = h.W2 + b2.
// 8 waves/block; wave w owns cols [w*32, w*32+32) x ALL 64 rows -> acc[4][2]
// (32 VGPRs), zero B duplication within a block (64 KB W-tile read once).
// x-tile staged once to LDS as bf16, XOR-swizzled (byte ^= (row&7)<<4) so the
// stride-256B ds_read_b128 A-fragments hit all 8 16B-slots evenly.
// A: row=lane&15, k=8*(lane>>4)+e. B: col=lane&15, same k. C/D: col=lane&15,
// row=(lane>>4)*4+q  (all verified by round-1 pass).
__global__ __launch_bounds__(512, 4) void kmain(
    const float* __restrict__ x, const float* __restrict__ b1,
    const float* __restrict__ W2, const float* __restrict__ b2,
    const unsigned short* __restrict__ W1T, const int* __restrict__ perm,
    const int* __restrict__ g_cnt, float* __restrict__ out) {
  __shared__ unsigned short xs[TM * FD];     // 16 KB swizzled bf16 x-tile
  __shared__ float s_red[TM][8];
  int t = threadIdx.x;

  for (int s = blockIdx.x; s < SLOTS; s += GRID_MAIN) {
    int d = s & 7, k = s >> 3;               // slot -> (domain, tile); active
    int rows = g_cnt[d] - k * TM;            // slots are contiguous in s
    if (rows <= 0) continue;
    rows = min(rows, TM);
    const int* pr = perm + (d << 16) + k * TM;
    const unsigned short* Wd = W1T + (size_t)d * HD * FD;

    // ---- stage x rows -> bf16 LDS (swizzled). 4 independent 16B gathers/thread.
    {
      int r = t >> 3, c8 = t & 7;
      int gi = pr[min(r, rows - 1)];
      const float* xr = x + (size_t)gi * FD;
      f32x4 v[4];
#pragma unroll
      for (int j = 0; j < 4; j++) v[j] = *(const f32x4*)(xr + (c8 + 8 * j) * 4);
#pragma unroll
      for (int j = 0; j < 4; j++) {
        int fc = c8 + 8 * j;
        int us = (r * FD + fc * 4) ^ ((r & 7) << 3);   // us-offset; ^bits3-5 = byte^bits4-6
        us4 wv;
        wv[0] = f2bf(v[j][0]); wv[1] = f2bf(v[j][1]);
        wv[2] = f2bf(v[j][2]); wv[3] = f2bf(v[j][3]);
        *(us4*)&xs[us] = wv;
      }
    }
    __syncthreads();

    int lane = t & 63, w = t >> 6;
    int lg = lane >> 4, lr = lane & 15;
    int colbase = w * 32;
    f32x4 acc[4][2];
#pragma unroll
    for (int mf = 0; mf < 4; mf++)
#pragma unroll
      for (int nt = 0; nt < 2; nt++) acc[mf][nt] = (f32x4){0.f, 0.f, 0.f, 0.f};

#pragma unroll
    for (int ks = 0; ks < 4; ks++) {
      bf16x8 a[4];
#pragma unroll
      for (int mf = 0; mf < 4; mf++) {
        int row = mf * 16 + lr;
        int us = (row * FD + ks * 32 + lg * 8) ^ ((row & 7) << 3);
        a[mf] = *(const bf16x8*)&xs[us];
      }
#pragma unroll
      for (int nt = 0; nt < 2; nt++) {
        int col = colbase + nt * 16 + lr;
        bf16x8 bfrag = *(const bf16x8*)(Wd + (size_t)col * FD + ks * 32 + lg * 8);
#pragma unroll
        for (int mf = 0; mf < 4; mf++)
          acc[mf][nt] = __builtin_amdgcn_mfma_f32_16x16x32_bf16(a[mf], bfrag, acc[mf][nt], 0, 0, 0);
      }
    }

    // ---- fused layer 2 (fp32): relu(acc + b1) . W2, 16-lane shfl reduce.
    float part[4][4];
#pragma unroll
    for (int mf = 0; mf < 4; mf++)
#pragma unroll
      for (int q = 0; q < 4; q++) part[mf][q] = 0.f;
#pragma unroll
    for (int nt = 0; nt < 2; nt++) {
      int col = colbase + nt * 16 + lr;
      float b1v = b1[d * HD + col];
      float w2v = W2[d * HD + col];
#pragma unroll
      for (int mf = 0; mf < 4; mf++)
#pragma unroll
        for (int q = 0; q < 4; q++) {
          float h = acc[mf][nt][q] + b1v;
          h = h > 0.f ? h : 0.f;
          part[mf][q] = fmaf(h, w2v, part[mf][q]);
        }
    }
#pragma unroll
    for (int off = 1; off < 16; off <<= 1)
#pragma unroll
      for (int mf = 0; mf < 4; mf++)
#pragma unroll
        for (int q = 0; q < 4; q++)
          part[mf][q] += __shfl_xor(part[mf][q], off);
    if (lr == 0) {
#pragma unroll
      for (int mf = 0; mf < 4; mf++)
#pragma unroll
        for (int q = 0; q < 4; q++)
          s_red[mf * 16 + lg * 4 + q][w] = part[mf][q];
    }
    __syncthreads();
    if (t < rows) {
      const float* sr = s_red[t];
      out[pr[t]] = sr[0] + sr[1] + sr[2] + sr[3] + sr[4] + sr[5] + sr[6] + sr[7]
                   + b2[d];
    }
    __syncthreads();   // protect xs/s_red before next grid-stride iteration
  }
}

extern "C" void kernel_launch(void* const* d_in, const int* in_sizes, int n_in,
                              void* d_out, int out_size, void* d_ws, size_t ws_size,
                              hipStream_t stream) {
  const float* x   = (const float*)d_in[0];
  const int*   ids = (const int*)d_in[1];
  const float* W1  = (const float*)d_in[2];
  const float* b1  = (const float*)d_in[3];
  const float* W2  = (const float*)d_in[4];
  const float* b2  = (const float*)d_in[5];
  float* out = (float*)d_out;

  // Workspace layout: [g_cnt 32B pad 1KB][perm 8*65536*4 = 2MB][W1T 512KB]
  char* ws = (char*)d_ws;
  int* g_cnt = (int*)ws;
  int* perm  = (int*)(ws + 1024);
  unsigned short* W1T = (unsigned short*)(ws + 1024 + (size_t)DN * BN * 4);

  hipMemsetAsync(g_cnt, 0, DN * sizeof(int), stream);
  hipLaunchKernelGGL(k_pre, dim3(BN / 256), dim3(256), 0, stream,
                     W1, ids, W1T, g_cnt, perm);
  hipLaunchKernelGGL(kmain, dim3(GRID_MAIN), dim3(512), 0, stream,
                     x, b1, W2, b2, W1T, perm, g_cnt, out);
}

// Round 3
// 102.690 us; speedup vs baseline: 1.2136x; 1.0256x over previous
//
#include <hip/hip_runtime.h>
#include <hip/hip_bf16.h>

// Problem constants (fixed by reference).
#define BN 65536   // batch
#define FD 128     // feature dim (K of layer 1)
#define HD 256     // hidden dim (N of layer 1)
#define DN 8       // domains
#define NB 256     // histogram blocks (BN / 256)
#define TM 64      // rows (samples) per main-kernel tile
#define GRID_MAIN 1024

typedef float f32x4 __attribute__((ext_vector_type(4)));
using bf16x8 = __attribute__((ext_vector_type(8))) __bf16;
typedef unsigned short us4 __attribute__((ext_vector_type(4)));

__device__ __forceinline__ unsigned short f2bf(float f) {
  unsigned int x = __float_as_uint(f);
  x += 0x7fffu + ((x >> 16) & 1u);   // round-to-nearest-even
  return (unsigned short)(x >> 16);
}

// ---- kA: blocks 0..255: per-block domain histogram (LDS atomics only, no
// global atomics -> no cross-XCD cacheline ping-pong). Blocks 256..287:
// W1 [d][f][h] f32 -> W1T [d][h][f] bf16 via LDS-tile transpose.
__global__ __launch_bounds__(256) void kA(
    const float* __restrict__ W1, const int* __restrict__ ids,
    unsigned short* __restrict__ W1T, int* __restrict__ cnt_blk) {
  __shared__ int hist[DN];
  __shared__ unsigned short tile[64][136];
  int t = threadIdx.x, bid = blockIdx.x;
  if (bid < NB) {
    if (t < DN) hist[t] = 0;
    __syncthreads();
    atomicAdd(&hist[ids[bid * 256 + t]], 1);
    __syncthreads();
    if (t < DN) cnt_blk[bid * DN + t] = hist[t];
  } else {
    int db = (bid - NB) >> 2, hb = (bid - NB) & 3;   // domain, h-quarter
    int fr = t >> 4, hq = t & 15;
    const float* src = W1 + (size_t)db * FD * HD + hb * 64 + hq * 4;
#pragma unroll
    for (int jj = 0; jj < 8; jj++) {
      int f = fr + 16 * jj;
      f32x4 v = *(const f32x4*)(src + (size_t)f * HD);
#pragma unroll
      for (int e = 0; e < 4; e++) tile[hq * 4 + e][f] = f2bf(v[e]);
    }
    __syncthreads();
    unsigned short* dst = W1T + (size_t)db * HD * FD + (size_t)hb * 64 * FD;
    int h = t >> 2, c = t & 3;
#pragma unroll
    for (int j = 0; j < 4; j++) {
      int f = c * 32 + j * 8;
      *(us4*)(dst + h * FD + f)     = *(const us4*)&tile[h][f];
      *(us4*)(dst + h * FD + f + 4) = *(const us4*)&tile[h][f + 4];
    }
  }
}

// ---- kB: single block. Per-domain exclusive scan over the 256 block counts
// (wave d scans domain d), domain totals, and exact tile list (d | k<<3).
__global__ __launch_bounds__(512) void kB(
    const int* __restrict__ cnt_blk, int* __restrict__ blk_base,
    int* __restrict__ g_cnt, int* __restrict__ tile_list,
    int* __restrict__ n_tiles) {
  __shared__ int s_cnt[DN], s_T[DN + 1];
  int t = threadIdx.x, d = t >> 6, l = t & 63;
  int c[4], sum = 0;
#pragma unroll
  for (int j = 0; j < 4; j++) { c[j] = cnt_blk[(l * 4 + j) * DN + d]; sum += c[j]; }
  int run = sum;
  for (int off = 1; off < 64; off <<= 1) {
    int v = __shfl_up(run, off);
    if (l >= off) run += v;
  }
  int excl = run - sum;
#pragma unroll
  for (int j = 0; j < 4; j++) { blk_base[(l * 4 + j) * DN + d] = excl; excl += c[j]; }
  if (l == 63) s_cnt[d] = run;
  __syncthreads();
  if (t == 0) {
    int T = 0;
    for (int dd = 0; dd < DN; dd++) {
      g_cnt[dd] = s_cnt[dd];
      s_T[dd] = T;
      T += (s_cnt[dd] + TM - 1) / TM;
    }
    s_T[DN] = T;
    *n_tiles = T;
  }
  __syncthreads();
  int T = s_T[DN];
  for (int tt = t; tt < T; tt += 512) {
    int dd = 0;
    while (s_T[dd + 1] <= tt) dd++;
    tile_list[tt] = dd | ((tt - s_T[dd]) << 3);
  }
}

// ---- kC: scatter sample ids into fixed per-domain regions perm[d<<16 ...].
// Local positions recomputed via LDS atomics (only intra-launch consistency
// needed); bases come from the deterministic scan.
__global__ __launch_bounds__(256) void kC(
    const int* __restrict__ ids, const int* __restrict__ blk_base,
    int* __restrict__ perm) {
  __shared__ int hist[DN], base[DN];
  int t = threadIdx.x, bid = blockIdx.x;
  if (t < DN) { hist[t] = 0; base[t] = (t << 16) + blk_base[bid * DN + t]; }
  __syncthreads();
  int i = bid * 256 + t;
  int id = ids[i];
  int lp = atomicAdd(&hist[id], 1);
  perm[base[id] + lp] = i;
}

// ---- kmain: per tile (domain d, 64 rows): h = relu(x W1 + b1); out = h.W2+b2.
// 8 waves; wave w owns cols [w*32,w*32+32) x all 64 rows -> acc[4][2].
// ILP structure: B-fragments (8 x b128), b1/W2 epilogue params, and the
// x-row gather are ALL issued before the staging barrier, so every global
// round trip overlaps the gather latency instead of serializing after it.
// A: row=lane&15, k=8*(lane>>4)+e. B: col=lane&15, same k. C/D: col=lane&15,
// row=(lane>>4)*4+q  (layouts verified by rounds 1-2 passing).
__global__ __launch_bounds__(512, 4) void kmain(
    const float* __restrict__ x, const float* __restrict__ b1,
    const float* __restrict__ W2, const float* __restrict__ b2,
    const unsigned short* __restrict__ W1T, const int* __restrict__ perm,
    const int* __restrict__ g_cnt, const int* __restrict__ tile_list,
    const int* __restrict__ n_tiles, float* __restrict__ out) {
  __shared__ unsigned short xs[TM * FD];     // 16 KB swizzled bf16 x-tile
  __shared__ float s_red[TM][9];             // padded: no bank conflict on row sum
  int T = *n_tiles;
  int t = threadIdx.x;
  int lane = t & 63, w = t >> 6;
  int lg = lane >> 4, lr = lane & 15;

  for (int i = blockIdx.x; i < T; i += GRID_MAIN) {
    int info = tile_list[i];
    int d = info & 7, k = info >> 3;
    int rows = min(g_cnt[d] - k * TM, TM);
    const int* pr = perm + (d << 16) + k * TM;
    const unsigned short* Wd = W1T + (size_t)d * HD * FD;

    // ---- hoisted loads: B fragments + epilogue params (independent of LDS).
    float b1v[2], w2v[2];
    bf16x8 bfr[4][2];
#pragma unroll
    for (int nt = 0; nt < 2; nt++) {
      int col = w * 32 + nt * 16 + lr;
      b1v[nt] = b1[d * HD + col];
      w2v[nt] = W2[d * HD + col];
#pragma unroll
      for (int ks = 0; ks < 4; ks++)
        bfr[ks][nt] = *(const bf16x8*)(Wd + (size_t)col * FD + ks * 32 + lg * 8);
    }

    // ---- stage x rows -> bf16 LDS (swizzled: us ^= (row&7)<<3).
    {
      int r = t >> 3, c8 = t & 7;
      int gi = pr[min(r, rows - 1)];
      const float* xr = x + (size_t)gi * FD;
      f32x4 v[4];
#pragma unroll
      for (int j = 0; j < 4; j++) v[j] = *(const f32x4*)(xr + (c8 + 8 * j) * 4);
#pragma unroll
      for (int j = 0; j < 4; j++) {
        int fc = c8 + 8 * j;
        int us = (r * FD + fc * 4) ^ ((r & 7) << 3);
        us4 wv;
        wv[0] = f2bf(v[j][0]); wv[1] = f2bf(v[j][1]);
        wv[2] = f2bf(v[j][2]); wv[3] = f2bf(v[j][3]);
        *(us4*)&xs[us] = wv;
      }
    }
    __syncthreads();

    f32x4 acc[4][2];
#pragma unroll
    for (int mf = 0; mf < 4; mf++)
#pragma unroll
      for (int nt = 0; nt < 2; nt++) acc[mf][nt] = (f32x4){0.f, 0.f, 0.f, 0.f};

#pragma unroll
    for (int ks = 0; ks < 4; ks++) {
      bf16x8 a[4];
#pragma unroll
      for (int mf = 0; mf < 4; mf++) {
        int row = mf * 16 + lr;
        int us = (row * FD + ks * 32 + lg * 8) ^ ((row & 7) << 3);
        a[mf] = *(const bf16x8*)&xs[us];
      }
#pragma unroll
      for (int nt = 0; nt < 2; nt++)
#pragma unroll
        for (int mf = 0; mf < 4; mf++)
          acc[mf][nt] = __builtin_amdgcn_mfma_f32_16x16x32_bf16(a[mf], bfr[ks][nt], acc[mf][nt], 0, 0, 0);
    }

    // ---- fused layer 2 (fp32): relu(acc + b1) . W2, 16-lane shfl reduce.
    float part[4][4];
#pragma unroll
    for (int mf = 0; mf < 4; mf++)
#pragma unroll
      for (int q = 0; q < 4; q++) part[mf][q] = 0.f;
#pragma unroll
    for (int nt = 0; nt < 2; nt++)
#pragma unroll
      for (int mf = 0; mf < 4; mf++)
#pragma unroll
        for (int q = 0; q < 4; q++) {
          float h = acc[mf][nt][q] + b1v[nt];
          h = h > 0.f ? h : 0.f;
          part[mf][q] = fmaf(h, w2v[nt], part[mf][q]);
        }
#pragma unroll
    for (int off = 1; off < 16; off <<= 1)
#pragma unroll
      for (int mf = 0; mf < 4; mf++)
#pragma unroll
        for (int q = 0; q < 4; q++)
          part[mf][q] += __shfl_xor(part[mf][q], off);
    if (lr == 0) {
#pragma unroll
      for (int mf = 0; mf < 4; mf++)
#pragma unroll
        for (int q = 0; q < 4; q++)
          s_red[mf * 16 + lg * 4 + q][w] = part[mf][q];
    }
    __syncthreads();
    if (t < rows) {
      const float* sr = s_red[t];
      out[pr[t]] = sr[0] + sr[1] + sr[2] + sr[3] + sr[4] + sr[5] + sr[6] + sr[7]
                   + b2[d];
    }
    __syncthreads();   // xs/s_red reused next grid-stride iteration
  }
}

extern "C" void kernel_launch(void* const* d_in, const int* in_sizes, int n_in,
                              void* d_out, int out_size, void* d_ws, size_t ws_size,
                              hipStream_t stream) {
  const float* x   = (const float*)d_in[0];
  const int*   ids = (const int*)d_in[1];
  const float* W1  = (const float*)d_in[2];
  const float* b1  = (const float*)d_in[3];
  const float* W2  = (const float*)d_in[4];
  const float* b2  = (const float*)d_in[5];
  float* out = (float*)d_out;

  // Workspace carve (ints). Every cell read is written first (ws is poisoned).
  int* ws_i = (int*)d_ws;
  int* g_cnt     = ws_i;            // 8
  int* n_tiles   = ws_i + 16;       // 1
  int* cnt_blk   = ws_i + 64;       // 2048
  int* blk_base  = ws_i + 2112;     // 2048
  int* tile_list = ws_i + 4160;     // <= 1031 (padded to 2048)
  int* perm      = ws_i + 8192;     // 8 * 65536
  unsigned short* W1T = (unsigned short*)(ws_i + 8192 + DN * BN);  // 512 KB, 16B-aligned

  hipLaunchKernelGGL(kA, dim3(NB + 32), dim3(256), 0, stream, W1, ids, W1T, cnt_blk);
  hipLaunchKernelGGL(kB, dim3(1), dim3(512), 0, stream, cnt_blk, blk_base, g_cnt,
                     tile_list, n_tiles);
  hipLaunchKernelGGL(kC, dim3(NB), dim3(256), 0, stream, ids, blk_base, perm);
  hipLaunchKernelGGL(kmain, dim3(GRID_MAIN), dim3(512), 0, stream, x, b1, W2, b2,
                     W1T, perm, g_cnt, tile_list, n_tiles, out);
}

// Round 4
// 100.053 us; speedup vs baseline: 1.2456x; 1.0264x over previous
//
#include <hip/hip_runtime.h>
#include <hip/hip_bf16.h>

// Problem constants (fixed by reference).
#define BN 65536   // batch
#define FD 128     // feature dim (K of layer 1)
#define HD 256     // hidden dim (N of layer 1)
#define DN 8       // domains
#define NB 256     // histogram blocks (BN / 256)
#define TM 64      // rows (samples) per main-kernel tile
#define SLOTS 8192 // worst-case (k,d) tile slots: 1024 tiles * 8 domains
#define GRID_MAIN 1024

typedef float f32x4 __attribute__((ext_vector_type(4)));
using bf16x8 = __attribute__((ext_vector_type(8))) __bf16;
typedef unsigned short us4 __attribute__((ext_vector_type(4)));

__device__ __forceinline__ unsigned short f2bf(float f) {
  unsigned int x = __float_as_uint(f);
  x += 0x7fffu + ((x >> 16) & 1u);   // round-to-nearest-even
  return (unsigned short)(x >> 16);
}

// ---- kA: blocks 0..255: per-block domain histogram (LDS atomics only).
// Blocks 256..287: W1 [d][f][h] f32 -> W1T [d][h][f] bf16 LDS-tile transpose.
__global__ __launch_bounds__(256) void kA(
    const float* __restrict__ W1, const int* __restrict__ ids,
    unsigned short* __restrict__ W1T, int* __restrict__ cnt_blk) {
  __shared__ int hist[DN];
  __shared__ unsigned short tile[64][136];
  int t = threadIdx.x, bid = blockIdx.x;
  if (bid < NB) {
    if (t < DN) hist[t] = 0;
    __syncthreads();
    atomicAdd(&hist[ids[bid * 256 + t]], 1);
    __syncthreads();
    if (t < DN) cnt_blk[bid * DN + t] = hist[t];
  } else {
    int db = (bid - NB) >> 2, hb = (bid - NB) & 3;   // domain, h-quarter
    int fr = t >> 4, hq = t & 15;
    const float* src = W1 + (size_t)db * FD * HD + hb * 64 + hq * 4;
#pragma unroll
    for (int jj = 0; jj < 8; jj++) {
      int f = fr + 16 * jj;
      f32x4 v = *(const f32x4*)(src + (size_t)f * HD);
#pragma unroll
      for (int e = 0; e < 4; e++) tile[hq * 4 + e][f] = f2bf(v[e]);
    }
    __syncthreads();
    unsigned short* dst = W1T + (size_t)db * HD * FD + (size_t)hb * 64 * FD;
    int h = t >> 2, c = t & 3;
#pragma unroll
    for (int j = 0; j < 4; j++) {
      int f = c * 32 + j * 8;
      *(us4*)(dst + h * FD + f)     = *(const us4*)&tile[h][f];
      *(us4*)(dst + h * FD + f + 4) = *(const us4*)&tile[h][f + 4];
    }
  }
}

// ---- kBC: fused scan + scatter. Each block computes its own per-domain
// exclusive prefix (sum of cnt_blk rows < bid) and the grand totals via
// lane-parallel loads + shfl reductions (wave w handles domains 2w, 2w+1),
// then scatters its 256 sample ids into fixed per-domain regions
// perm[d<<16 ...]. Block 0 publishes g_cnt. Deterministic, no global atomics,
// no whole-GPU-idle serial scan kernel.
__global__ __launch_bounds__(256) void kBC(
    const int* __restrict__ ids, const int* __restrict__ cnt_blk,
    int* __restrict__ g_cnt, int* __restrict__ perm) {
  __shared__ int s_before[DN], s_total[DN], hist[DN];
  int t = threadIdx.x, bid = blockIdx.x;
  int w = t >> 6, l = t & 63;
  int full0 = 0, full1 = 0, bef0 = 0, bef1 = 0;
#pragma unroll
  for (int j = 0; j < 4; j++) {
    int r = l * 4 + j;
    int2 v = *(const int2*)(cnt_blk + r * DN + 2 * w);
    full0 += v.x; full1 += v.y;
    if (r < bid) { bef0 += v.x; bef1 += v.y; }
  }
#pragma unroll
  for (int off = 1; off < 64; off <<= 1) {
    full0 += __shfl_xor(full0, off); full1 += __shfl_xor(full1, off);
    bef0  += __shfl_xor(bef0, off);  bef1  += __shfl_xor(bef1, off);
  }
  if (t < DN) hist[t] = 0;
  if (l == 0) {
    s_before[2 * w] = bef0; s_before[2 * w + 1] = bef1;
    s_total[2 * w] = full0; s_total[2 * w + 1] = full1;
  }
  __syncthreads();
  int i = bid * 256 + t;
  int id = ids[i];
  int lp = atomicAdd(&hist[id], 1);          // LDS atomic only
  perm[(id << 16) + s_before[id] + lp] = i;
  if (bid == 0 && t < DN) g_cnt[t] = s_total[t];
}

// ---- kmain: self-scheduled over the (k,d) slot space using only g_cnt.
// Slot s -> d = s&7, k = s>>3; active iff k*TM < g_cnt[d]. With balanced
// counts, slots 0..~1030 are active -> each block handles ~1 real tile and
// skips the rest with a block-uniform cheap probe.
// Per tile (domain d, 64 rows): h = relu(x W1 + b1); out = h.W2 + b2.
// 8 waves; wave w owns cols [w*32,w*32+32) x all 64 rows -> acc[4][2].
// B fragments + epilogue params hoisted before the staging barrier (ILP).
// A: row=lane&15, k=8*(lane>>4)+e. B: col=lane&15, same k. C/D: col=lane&15,
// row=(lane>>4)*4+q  (layouts verified rounds 1-3).
__global__ __launch_bounds__(512, 4) void kmain(
    const float* __restrict__ x, const float* __restrict__ b1,
    const float* __restrict__ W2, const float* __restrict__ b2,
    const unsigned short* __restrict__ W1T, const int* __restrict__ perm,
    const int* __restrict__ g_cnt, float* __restrict__ out) {
  __shared__ unsigned short xs[TM * FD];     // 16 KB swizzled bf16 x-tile
  __shared__ float s_red[TM][9];             // padded row-sum staging
  int t = threadIdx.x;
  int lane = t & 63, w = t >> 6;
  int lg = lane >> 4, lr = lane & 15;

  for (int s = blockIdx.x; s < SLOTS; s += GRID_MAIN) {
    int d = s & 7, k = s >> 3;
    int rows = g_cnt[d] - k * TM;            // block-uniform
    if (rows <= 0) continue;
    rows = min(rows, TM);
    const int* pr = perm + (d << 16) + k * TM;
    const unsigned short* Wd = W1T + (size_t)d * HD * FD;

    // ---- hoisted loads: B fragments + epilogue params (independent of LDS).
    float b1v[2], w2v[2];
    bf16x8 bfr[4][2];
#pragma unroll
    for (int nt = 0; nt < 2; nt++) {
      int col = w * 32 + nt * 16 + lr;
      b1v[nt] = b1[d * HD + col];
      w2v[nt] = W2[d * HD + col];
#pragma unroll
      for (int ks = 0; ks < 4; ks++)
        bfr[ks][nt] = *(const bf16x8*)(Wd + (size_t)col * FD + ks * 32 + lg * 8);
    }

    // ---- stage x rows -> bf16 LDS (swizzled: us ^= (row&7)<<3).
    {
      int r = t >> 3, c8 = t & 7;
      int gi = pr[min(r, rows - 1)];
      const float* xr = x + (size_t)gi * FD;
      f32x4 v[4];
#pragma unroll
      for (int j = 0; j < 4; j++) v[j] = *(const f32x4*)(xr + (c8 + 8 * j) * 4);
#pragma unroll
      for (int j = 0; j < 4; j++) {
        int fc = c8 + 8 * j;
        int us = (r * FD + fc * 4) ^ ((r & 7) << 3);
        us4 wv;
        wv[0] = f2bf(v[j][0]); wv[1] = f2bf(v[j][1]);
        wv[2] = f2bf(v[j][2]); wv[3] = f2bf(v[j][3]);
        *(us4*)&xs[us] = wv;
      }
    }
    __syncthreads();

    f32x4 acc[4][2];
#pragma unroll
    for (int mf = 0; mf < 4; mf++)
#pragma unroll
      for (int nt = 0; nt < 2; nt++) acc[mf][nt] = (f32x4){0.f, 0.f, 0.f, 0.f};

#pragma unroll
    for (int ks = 0; ks < 4; ks++) {
      bf16x8 a[4];
#pragma unroll
      for (int mf = 0; mf < 4; mf++) {
        int row = mf * 16 + lr;
        int us = (row * FD + ks * 32 + lg * 8) ^ ((row & 7) << 3);
        a[mf] = *(const bf16x8*)&xs[us];
      }
#pragma unroll
      for (int nt = 0; nt < 2; nt++)
#pragma unroll
        for (int mf = 0; mf < 4; mf++)
          acc[mf][nt] = __builtin_amdgcn_mfma_f32_16x16x32_bf16(a[mf], bfr[ks][nt], acc[mf][nt], 0, 0, 0);
    }

    // ---- fused layer 2 (fp32): relu(acc + b1) . W2, 16-lane shfl reduce.
    float part[4][4];
#pragma unroll
    for (int mf = 0; mf < 4; mf++)
#pragma unroll
      for (int q = 0; q < 4; q++) part[mf][q] = 0.f;
#pragma unroll
    for (int nt = 0; nt < 2; nt++)
#pragma unroll
      for (int mf = 0; mf < 4; mf++)
#pragma unroll
        for (int q = 0; q < 4; q++) {
          float h = acc[mf][nt][q] + b1v[nt];
          h = h > 0.f ? h : 0.f;
          part[mf][q] = fmaf(h, w2v[nt], part[mf][q]);
        }
#pragma unroll
    for (int off = 1; off < 16; off <<= 1)
#pragma unroll
      for (int mf = 0; mf < 4; mf++)
#pragma unroll
        for (int q = 0; q < 4; q++)
          part[mf][q] += __shfl_xor(part[mf][q], off);
    if (lr == 0) {
#pragma unroll
      for (int mf = 0; mf < 4; mf++)
#pragma unroll
        for (int q = 0; q < 4; q++)
          s_red[mf * 16 + lg * 4 + q][w] = part[mf][q];
    }
    __syncthreads();
    if (t < rows) {
      const float* sr = s_red[t];
      out[pr[t]] = sr[0] + sr[1] + sr[2] + sr[3] + sr[4] + sr[5] + sr[6] + sr[7]
                   + b2[d];
    }
    __syncthreads();   // xs/s_red reused next grid-stride iteration
  }
}

extern "C" void kernel_launch(void* const* d_in, const int* in_sizes, int n_in,
                              void* d_out, int out_size, void* d_ws, size_t ws_size,
                              hipStream_t stream) {
  const float* x   = (const float*)d_in[0];
  const int*   ids = (const int*)d_in[1];
  const float* W1  = (const float*)d_in[2];
  const float* b1  = (const float*)d_in[3];
  const float* W2  = (const float*)d_in[4];
  const float* b2  = (const float*)d_in[5];
  float* out = (float*)d_out;

  // Workspace carve (ints). Every cell read is written first (ws is poisoned).
  int* ws_i = (int*)d_ws;
  int* cnt_blk = ws_i;              // 2048
  int* g_cnt   = ws_i + 2048;       // 8
  int* perm    = ws_i + 4096;       // 8 * 65536  (2 MB, 16B-aligned)
  unsigned short* W1T = (unsigned short*)(ws_i + 4096 + DN * BN);  // 512 KB

  hipLaunchKernelGGL(kA, dim3(NB + 32), dim3(256), 0, stream, W1, ids, W1T, cnt_blk);
  hipLaunchKernelGGL(kBC, dim3(NB), dim3(256), 0, stream, ids, cnt_blk, g_cnt, perm);
  hipLaunchKernelGGL(kmain, dim3(GRID_MAIN), dim3(512), 0, stream, x, b1, W2, b2,
                     W1T, perm, g_cnt, out);
}